// Round 8
// baseline (187.151 us; speedup 1.0000x reference)
//
#include <hip/hip_runtime.h>
#include <stdint.h>

#define N_V   4096
#define T_PER 4
#define NT    16384
#define D_K   256
#define SCALE 10.0f   // 1/temperature
#define LOG2E 1.44269504088896340736f
#define LN2   0.69314718055994530942f

#if defined(__has_builtin)
#if __has_builtin(__builtin_amdgcn_exp2f)
#define EXP2F(x) __builtin_amdgcn_exp2f(x)
#endif
#endif
#ifndef EXP2F
#define EXP2F(x) exp2f(x)
#endif

typedef __bf16 bf16x8 __attribute__((ext_vector_type(8)));
typedef float  f32x4  __attribute__((ext_vector_type(4)));

// ---------------- DPP cross-lane reduces (VALU pipe, zero DS traffic) --------------------
// row_ror:N (0x120|N) rotates within each 16-lane DPP row; rotation-reduce over {1,2,4,8}
// converges every lane of the row to the 16-lane result.
// r3 lesson: row_bcast15/31 broadcasts a single lane — NOT a per-lane ±16 exchange.
// r4 lesson: thresholds are v·t with independent t — counts are dense, no gating valid.
// r5 lesson: VGPR+AGPR budget at 4 waves/EU is 128 = exactly 64+64 here; never raise it.
// r6/r7 lesson: k_gemm noise band ±2.5 us; launch-removal saves ~1 us, not 10; the ~70 us
//               residual is k_prep + latency-bound k_redfin + fixed graph overhead.
template<int C>
__device__ __forceinline__ float dppf(float v) {
  return __int_as_float(__builtin_amdgcn_update_dpp(
      0, __float_as_int(v), C, 0xf, 0xf, true));
}
template<int C>
__device__ __forceinline__ uint32_t dppu(uint32_t v) {
  return (uint32_t)__builtin_amdgcn_update_dpp(0, (int)v, C, 0xf, 0xf, true);
}
__device__ __forceinline__ float max16(float v) {
  v = fmaxf(v, dppf<0x121>(v));
  v = fmaxf(v, dppf<0x122>(v));
  v = fmaxf(v, dppf<0x124>(v));
  v = fmaxf(v, dppf<0x128>(v));
  return v;
}
__device__ __forceinline__ float sum16f(float v) {
  v += dppf<0x121>(v); v += dppf<0x122>(v);
  v += dppf<0x124>(v); v += dppf<0x128>(v);
  return v;
}
__device__ __forceinline__ uint32_t sum16u(uint32_t v) {
  v += dppu<0x121>(v); v += dppu<0x122>(v);
  v += dppu<0x124>(v); v += dppu<0x128>(v);
  return v;
}

__device__ __forceinline__ unsigned short f2bf(float f) {
  uint32_t u = __float_as_uint(f);
  u = (u + 0x7fffu + ((u >> 16) & 1u)) >> 16;   // RNE
  return (unsigned short)u;
}

// ---------------- A: fused convert + diagonal dots (reads v,t exactly once) ---------------
// A-side bf16 carries SCALE*LOG2E so GEMM scores come out in log2 domain.
__global__ void k_prep(const float* __restrict__ v, const float* __restrict__ t,
                       unsigned short* __restrict__ Abf, unsigned short* __restrict__ Bbf,
                       float* __restrict__ thr, float* __restrict__ nom,
                       float* __restrict__ out) {
  const int tid = threadIdx.x, l = tid & 63, w = tid >> 6;
  const int i = blockIdx.x * 4 + w;            // one wave per video
  if (blockIdx.x == 0 && tid < 5) out[tid] = 0.0f;
  const float AS = SCALE * LOG2E;

  float4 a = ((const float4*)(v + (size_t)i * D_K))[l];
  ushort4 oa;
  oa.x = f2bf(a.x * AS); oa.y = f2bf(a.y * AS);
  oa.z = f2bf(a.z * AS); oa.w = f2bf(a.w * AS);
  ((ushort4*)(Abf + (size_t)i * D_K))[l] = oa;

  float tv[T_PER];
#pragma unroll
  for (int tt = 0; tt < T_PER; ++tt) {
    float4 b = ((const float4*)(t + (size_t)(i * T_PER + tt) * D_K))[l];
    ushort4 ob;
    ob.x = f2bf(b.x); ob.y = f2bf(b.y); ob.z = f2bf(b.z); ob.w = f2bf(b.w);
    ((ushort4*)(Bbf + (size_t)(i * T_PER + tt) * D_K))[l] = ob;
    float d = a.x * b.x + a.y * b.y + a.z * b.z + a.w * b.w;
#pragma unroll
    for (int s = 1; s < 64; s <<= 1) d += __shfl_xor(d, s);
    tv[tt] = d * SCALE;                        // natural-domain score
  }
  if (l == 0) {
    ((float4*)thr)[i] = make_float4(tv[0] * LOG2E, tv[1] * LOG2E,
                                    tv[2] * LOG2E, tv[3] * LOG2E);
    float m = fmaxf(fmaxf(tv[0], tv[1]), fmaxf(tv[2], tv[3]));
    float e = __expf(tv[0] - m) + __expf(tv[1] - m) + __expf(tv[2] - m) + __expf(tv[3] - m);
    nom[i] = m + __logf(e);
  }
}

// ---------------- B: barrier-free K-loop GEMM, 2 col-tiles per block ----------------------
// Block = 64 rows x 512 cols (2 sequential 64x256 tiles). The 32 KB A-tile is staged ONCE
// and reused by both tiles' K-loops — staging + vmcnt drain + launch amortized 2x. acc is
// reused sequentially (arch VGPR stays 64; r5: total budget 128 = 64+64acc at 4 waves/EU).
// Tile-1's first B chunks are issued before the inter-tile barrier -> overlap combine.
__device__ __forceinline__ void gld16(const void* g, void* l) {
  __builtin_amdgcn_global_load_lds((const __attribute__((address_space(1))) void*)g,
                                   (__attribute__((address_space(3))) void*)l,
                                   16, 0, 0);
}

__global__ __launch_bounds__(256, 4) void k_gemm(
    const unsigned short* __restrict__ Abf, const unsigned short* __restrict__ Bbf,
    const float* __restrict__ thr,
    float* __restrict__ pmax, float* __restrict__ psum, uint4* __restrict__ pcnt,
    float* __restrict__ cmax, float* __restrict__ csum) {
  __shared__ __align__(16) unsigned short As[64 * 256];   // 32 KB, swizzled full-K A tile
  __shared__ float4   thrS[64];
  __shared__ float    rowMw[4][64], rowEw[4][64];
  __shared__ uint32_t rowCw[4][64];

  const int ct = blockIdx.x, rt = blockIdx.y;
  const int row0 = rt * 64;
  const int tid = threadIdx.x;
  const int l = tid & 63, w = tid >> 6;
  const int quad = l >> 4, nl = l & 15;

  if (tid < 64) thrS[tid] = ((const float4*)thr)[row0 + tid];

  // ---- stage A once: 32 groups of 1024 B; group g = (rowset rs = g>>2, k-span ks = g&3).
  // Lane l = lr*8+lc writes 16B chunk (lc^lr) of row lr at slot l*16 (XOR swizzle keeps
  // both the wave-uniform gld16 placement AND conflict-free ds_read_b128 later).
  const int lr = l >> 3, lc7 = l & 7;
  const int sc = lc7 ^ lr;
#pragma unroll
  for (int it = 0; it < 8; ++it) {
    int g = w * 8 + it;
    int rs = g >> 2, ks = g & 3;
    const unsigned short* ga =
        Abf + (size_t)(row0 + rs * 8 + lr) * D_K + ks * 64 + sc * 8;
    gld16(ga, (char*)As + g * 1024);
  }

#pragma unroll
  for (int tile = 0; tile < 2; ++tile) {
    const int col0 = ct * 512 + tile * 256;
    const int ctp = ct * 2 + tile;             // partial-slot index (0..63)

    f32x4 acc[4][4];
#pragma unroll
    for (int i = 0; i < 4; ++i)
#pragma unroll
      for (int j = 0; j < 4; ++j) acc[i][j] = {0.f, 0.f, 0.f, 0.f};

    // per-lane B pointers: col = col0 + w*64 + j*16 + nl, k = quad*8 (+ chunk offsets)
    const unsigned short* pB[4];
#pragma unroll
    for (int j = 0; j < 4; ++j)
      pB[j] = Bbf + (size_t)(col0 + w * 64 + j * 16 + nl) * D_K + quad * 8;

    // First two B chunks issued BEFORE the barrier: tile0 rides the A-stage vmcnt drain,
    // tile1 overlaps wave0's tile-0 combine.
    bf16x8 bv[3][4];
#pragma unroll
    for (int j = 0; j < 4; ++j) bv[0][j] = *(const bf16x8*)(pB[j]);
#pragma unroll
    for (int j = 0; j < 4; ++j) bv[1][j] = *(const bf16x8*)(pB[j] + 32);

    __syncthreads();   // tile0: A staged; tile1: rowMw free (tile0 combine done)

    __builtin_amdgcn_s_setprio(1);
#pragma unroll
    for (int c = 0; c < 8; ++c) {               // 8 chunks of K=32
      if (c < 6) {
#pragma unroll
        for (int j = 0; j < 4; ++j)
          bv[(c + 2) % 3][j] = *(const bf16x8*)(pB[j] + (c + 2) * 32);
      }
      bf16x8 af[4];
#pragma unroll
      for (int i = 0; i < 4; ++i) {
        int r = i * 16 + nl;
        int rb = r & 7;
        int grp = (r >> 3) * 4 + (c >> 1);
        int cc = ((((c & 1) << 2) | quad) ^ rb);
        af[i] = *(const bf16x8*)((const char*)As + grp * 1024 + (rb * 8 + cc) * 16);
      }
#pragma unroll
      for (int i = 0; i < 4; ++i)
#pragma unroll
        for (int j = 0; j < 4; ++j)
          acc[i][j] = __builtin_amdgcn_mfma_f32_16x16x32_bf16(af[i], bv[c % 3][j],
                                                              acc[i][j], 0, 0, 0);
    }
    __builtin_amdgcn_s_setprio(0);

    // ================= epilogue (scores in log2 domain) =================
    // C/D layout: col = nl, row = quad*4 + reg. Per-row/per-col maxes mandatory
    // (shared max underflows exp2 -> log(0) downstream).

#pragma unroll
    for (int i = 0; i < 4; ++i) {
#pragma unroll
      for (int r = 0; r < 4; ++r) {
        const int row = i * 16 + quad * 4 + r;
        float4 th = thrS[row];                 // 16-lane broadcast read, conflict-free
        float s0 = acc[i][0][r], s1 = acc[i][1][r];
        float s2 = acc[i][2][r], s3 = acc[i][3][r];
        uint32_t c0 = (uint32_t)(s0 > th.x) + (uint32_t)(s1 > th.x)
                    + (uint32_t)(s2 > th.x) + (uint32_t)(s3 > th.x);
        uint32_t c1 = (uint32_t)(s0 > th.y) + (uint32_t)(s1 > th.y)
                    + (uint32_t)(s2 > th.y) + (uint32_t)(s3 > th.y);
        uint32_t c2 = (uint32_t)(s0 > th.z) + (uint32_t)(s1 > th.z)
                    + (uint32_t)(s2 > th.z) + (uint32_t)(s3 > th.z);
        uint32_t c3 = (uint32_t)(s0 > th.w) + (uint32_t)(s1 > th.w)
                    + (uint32_t)(s2 > th.w) + (uint32_t)(s3 > th.w);
        uint32_t c = c0 + (c1 << 8) + (c2 << 16) + (c3 << 24);
        c = sum16u(c);                         // fields <= 64, no overflow
        float m = fmaxf(fmaxf(s0, s1), fmaxf(s2, s3));
        m = max16(m);                          // all 16 lanes get the row max
        float e = (EXP2F(s0 - m) + EXP2F(s1 - m)) + (EXP2F(s2 - m) + EXP2F(s3 - m));
        e = sum16f(e);
        if (nl == 0) {
          rowMw[w][row] = m; rowEw[w][row] = e; rowCw[w][row] = c;
        }
      }
    }

    // col partials: whole 64-row column lives in this wave -> direct global write.
#pragma unroll
    for (int j = 0; j < 4; ++j) {
      float m = -3.0e38f;
#pragma unroll
      for (int i = 0; i < 4; ++i)
#pragma unroll
        for (int r = 0; r < 4; ++r) m = fmaxf(m, acc[i][j][r]);
      m = fmaxf(m, __shfl_xor(m, 16));
      m = fmaxf(m, __shfl_xor(m, 32));
      float e = 0.f;
#pragma unroll
      for (int i = 0; i < 4; ++i)
#pragma unroll
        for (int r = 0; r < 4; ++r) e += EXP2F(acc[i][j][r] - m);
      e += __shfl_xor(e, 16);
      e += __shfl_xor(e, 32);
      if (quad == 0) {
        int colg = col0 + w * 64 + j * 16 + nl;
        size_t gi = (size_t)rt * NT + colg;
        cmax[gi] = m; csum[gi] = e;
      }
    }
    __syncthreads();

    // combine the 4 col-strips per row; counts unpacked to 32-bit (4x64 would overflow 8b)
    if (tid < 64) {
      float M0 = rowMw[0][tid], M1 = rowMw[1][tid], M2 = rowMw[2][tid], M3 = rowMw[3][tid];
      float Mx = fmaxf(fmaxf(M0, M1), fmaxf(M2, M3));
      float Sx = rowEw[0][tid] * EXP2F(M0 - Mx) + rowEw[1][tid] * EXP2F(M1 - Mx)
               + rowEw[2][tid] * EXP2F(M2 - Mx) + rowEw[3][tid] * EXP2F(M3 - Mx);
      uint32_t c0 = 0, c1 = 0, c2 = 0, c3 = 0;
#pragma unroll
      for (int ww = 0; ww < 4; ++ww) {
        uint32_t cc = rowCw[ww][tid];
        c0 += cc & 0xffu; c1 += (cc >> 8) & 0xffu;
        c2 += (cc >> 16) & 0xffu; c3 += cc >> 24;
      }
      size_t gi = (size_t)ctp * N_V + row0 + tid;
      pmax[gi] = Mx; psum[gi] = Sx; pcnt[gi] = make_uint4(c0, c1, c2, c3);
    }
  }
}

// ---------------- C: fused row+col reduction AND finale -----------------------------------
// 256 blocks x 256 threads (was 64 blocks): block b owns rows [16b,16b+16) and cols
// [64b,64b+64); the finale for row r needs exactly cols 4r..4r+3 = local [4*rloc..+3].
// 4x CU coverage and per-thread load count 80 -> ~35 attacks the latency-bound residual.
__global__ void k_redfin(const float* __restrict__ pmax, const float* __restrict__ psum,
                         const uint4* __restrict__ pcnt,
                         const float* __restrict__ cmax, const float* __restrict__ csum,
                         const float* __restrict__ nom, float* __restrict__ out) {
  __shared__ float Lm[16][16], Ls[16][16];
  __shared__ uint4 Lc[16][16];
  __shared__ float Cm[4][64], Cs[4][64];
  __shared__ float colM[64], colS[64];
  const int b = blockIdx.x, tid = threadIdx.x;

  // ---- row partials: 16 rows x 64 partials; thread (rloc, chunk) covers 4 partials
  {
    const int rloc = tid & 15, chunk = tid >> 4;
    const int row = b * 16 + rloc;
    float mv[4];
#pragma unroll
    for (int k = 0; k < 4; ++k)
      mv[k] = pmax[(size_t)(chunk * 4 + k) * N_V + row];
    float M = fmaxf(fmaxf(mv[0], mv[1]), fmaxf(mv[2], mv[3]));
    float S = 0.f;
    uint32_t c0 = 0, c1 = 0, c2 = 0, c3 = 0;
#pragma unroll
    for (int k = 0; k < 4; ++k) {
      size_t idx = (size_t)(chunk * 4 + k) * N_V + row;
      S += psum[idx] * EXP2F(mv[k] - M);
      uint4 cc = pcnt[idx];
      c0 += cc.x; c1 += cc.y; c2 += cc.z; c3 += cc.w;
    }
    Lm[chunk][rloc] = M; Ls[chunk][rloc] = S;
    Lc[chunk][rloc] = make_uint4(c0, c1, c2, c3);
  }

  // ---- col partials: 64 cols x 64 partials; thread (cloc, h) covers 16 partials
  {
    const int cloc = tid & 63, h = tid >> 6;
    const int col = b * 64 + cloc;
    float mv[16];
#pragma unroll
    for (int k = 0; k < 16; ++k)
      mv[k] = cmax[(size_t)(h * 16 + k) * NT + col];
    float tm[8];
#pragma unroll
    for (int k = 0; k < 8; ++k) tm[k] = fmaxf(mv[k], mv[k + 8]);
#pragma unroll
    for (int k = 0; k < 4; ++k) tm[k] = fmaxf(tm[k], tm[k + 4]);
    float M = fmaxf(fmaxf(tm[0], tm[1]), fmaxf(tm[2], tm[3]));
    float S = 0.f;
#pragma unroll
    for (int k = 0; k < 16; ++k)
      S += csum[(size_t)(h * 16 + k) * NT + col] * EXP2F(mv[k] - M);
    Cm[h][cloc] = M; Cs[h][cloc] = S;
  }
  __syncthreads();

  // ---- combine cols (tid<64) and rows (tid<16, kept in registers for the finale)
  if (tid < 64) {
    float M0 = Cm[0][tid], M1 = Cm[1][tid], M2 = Cm[2][tid], M3 = Cm[3][tid];
    float Mx = fmaxf(fmaxf(M0, M1), fmaxf(M2, M3));
    float Sx = Cs[0][tid] * EXP2F(M0 - Mx) + Cs[1][tid] * EXP2F(M1 - Mx)
             + Cs[2][tid] * EXP2F(M2 - Mx) + Cs[3][tid] * EXP2F(M3 - Mx);
    colM[tid] = Mx; colS[tid] = Sx;
  }
  float rM = -3.0e38f, rS = 0.f;
  uint4 rC = make_uint4(0, 0, 0, 0);
  if (tid < 16) {
    float m8[8];
#pragma unroll
    for (int c = 0; c < 8; ++c) m8[c] = fmaxf(Lm[c][tid], Lm[c + 8][tid]);
#pragma unroll
    for (int c = 0; c < 4; ++c) m8[c] = fmaxf(m8[c], m8[c + 4]);
    rM = fmaxf(fmaxf(m8[0], m8[1]), fmaxf(m8[2], m8[3]));
#pragma unroll
    for (int c = 0; c < 16; ++c) {
      rS += Ls[c][tid] * EXP2F(Lm[c][tid] - rM);
      uint4 cc = Lc[c][tid];
      rC.x += cc.x; rC.y += cc.y; rC.z += cc.z; rC.w += cc.w;
    }
  }
  __syncthreads();

  // ---- finale for this block's 16 rows (lanes 0-15 of wave 0 = one DPP row)
  if (tid < 16) {
    int row = b * 16 + tid;
    float cm0 = colM[tid * 4 + 0], cm1 = colM[tid * 4 + 1];
    float cm2 = colM[tid * 4 + 2], cm3 = colM[tid * 4 + 3];
    float cs0 = colS[tid * 4 + 0], cs1 = colS[tid * 4 + 1];
    float cs2 = colS[tid * 4 + 2], cs3 = colS[tid * 4 + 3];
    float Mp = fmaxf(rM, fmaxf(fmaxf(cm0, cm1), fmaxf(cm2, cm3)));
    float tot = rS * EXP2F(rM - Mp)
              + cs0 * EXP2F(cm0 - Mp) + cs1 * EXP2F(cm1 - Mp)
              + cs2 * EXP2F(cm2 - Mp) + cs3 * EXP2F(cm3 - Mp);
    float ll = LN2 * (Mp + __log2f(tot)) - nom[row];   // log2-domain LSE -> ln
    float ar  = (float)(rC.x + rC.y + rC.z + rC.w) * 0.25f;
    float r1  = (float)((rC.x < 1u) + (rC.y < 1u) + (rC.z < 1u) + (rC.w < 1u)) * 0.25f;
    float r5  = (float)((rC.x < 5u) + (rC.y < 5u) + (rC.z < 5u) + (rC.w < 5u)) * 0.25f;
    float r10 = (float)((rC.x < 10u) + (rC.y < 10u) + (rC.z < 10u) + (rC.w < 10u)) * 0.25f;
    float vals[5] = {ll, r1, r5, r10, ar};
#pragma unroll
    for (int k = 0; k < 5; ++k) {
      float v = sum16f(vals[k]);               // lanes 0-15 are DPP row 0
      if (tid == 0) atomicAdd(&out[k], v * (1.0f / N_V));
    }
  }
}

extern "C" void kernel_launch(void* const* d_in, const int* in_sizes, int n_in,
                              void* d_out, int out_size, void* d_ws, size_t ws_size,
                              hipStream_t stream) {
  const float* v = (const float*)d_in[0];
  const float* t = (const float*)d_in[1];
  char* p = (char*)d_ws;
  unsigned short* Abf = (unsigned short*)p; p += (size_t)N_V * D_K * 2;
  unsigned short* Bbf = (unsigned short*)p; p += (size_t)NT * D_K * 2;
  float* thr  = (float*)p;    p += (size_t)N_V * 4 * 4;
  float* nom  = (float*)p;    p += (size_t)N_V * 4;
  float* pmax = (float*)p;    p += (size_t)64 * N_V * 4;
  float* psum = (float*)p;    p += (size_t)64 * N_V * 4;
  uint4* pcnt = (uint4*)p;    p += (size_t)64 * N_V * 16;
  float* cmaxp = (float*)p;   p += (size_t)64 * NT * 4;
  float* csump = (float*)p;   p += (size_t)64 * NT * 4;
  // total ws: ~26 MB

  k_prep<<<N_V / 4, 256, 0, stream>>>(v, t, Abf, Bbf, thr, nom, (float*)d_out);
  dim3 g(NT / 512, N_V / 64);                     // ct x rt = 32 x 64 (2 col-tiles/block)
  k_gemm<<<g, 256, 0, stream>>>(Abf, Bbf, thr, pmax, psum, pcnt, cmaxp, csump);
  k_redfin<<<N_V / 16, 256, 0, stream>>>(pmax, psum, pcnt, cmaxp, csump, nom,
                                         (float*)d_out);
}

// Round 9
// 155.495 us; speedup vs baseline: 1.2036x; 1.2036x over previous
//
#include <hip/hip_runtime.h>
#include <stdint.h>

#define N_V   4096
#define T_PER 4
#define NT    16384
#define D_K   256
#define SCALE 10.0f   // 1/temperature
#define LOG2E 1.44269504088896340736f
#define LN2   0.69314718055994530942f

#if defined(__has_builtin)
#if __has_builtin(__builtin_amdgcn_exp2f)
#define EXP2F(x) __builtin_amdgcn_exp2f(x)
#endif
#endif
#ifndef EXP2F
#define EXP2F(x) exp2f(x)
#endif

typedef __bf16 bf16x8 __attribute__((ext_vector_type(8)));
typedef float  f32x4  __attribute__((ext_vector_type(4)));

// ---------------- DPP cross-lane reduces (VALU pipe, zero DS traffic) --------------------
// row_ror:N (0x120|N) rotates within each 16-lane DPP row; rotation-reduce over {1,2,4,8}
// converges every lane of the row to the full 16-lane result (no broadcast needed). Our
// reduce groups are quad*16+nl = exactly DPP rows. This replaced the 12-deep dependent
// ds_swizzle chains that made the epilogue latency-bound (r0: 125.8 -> r1: 86.4 us).
// Session lessons encoded here:
//  r3: row_bcast15/31 broadcasts a single lane — NOT a per-lane ±16 exchange.
//  r4: thresholds are v·t with independent t — counts are dense; no threshold gating.
//  r5: VGPR+AGPR budget at 4 waves/EU is 128 = exactly 64+64 here; never raise waves/EU.
//  r8: keeping a second tile's prefetch live across the epilogue spills (~38 B/thread).
template<int C>
__device__ __forceinline__ float dppf(float v) {
  return __int_as_float(__builtin_amdgcn_update_dpp(
      0, __float_as_int(v), C, 0xf, 0xf, true));
}
template<int C>
__device__ __forceinline__ uint32_t dppu(uint32_t v) {
  return (uint32_t)__builtin_amdgcn_update_dpp(0, (int)v, C, 0xf, 0xf, true);
}
__device__ __forceinline__ float max16(float v) {
  v = fmaxf(v, dppf<0x121>(v));
  v = fmaxf(v, dppf<0x122>(v));
  v = fmaxf(v, dppf<0x124>(v));
  v = fmaxf(v, dppf<0x128>(v));
  return v;
}
__device__ __forceinline__ float sum16f(float v) {
  v += dppf<0x121>(v); v += dppf<0x122>(v);
  v += dppf<0x124>(v); v += dppf<0x128>(v);
  return v;
}
__device__ __forceinline__ uint32_t sum16u(uint32_t v) {
  v += dppu<0x121>(v); v += dppu<0x122>(v);
  v += dppu<0x124>(v); v += dppu<0x128>(v);
  return v;
}

__device__ __forceinline__ unsigned short f2bf(float f) {
  uint32_t u = __float_as_uint(f);
  u = (u + 0x7fffu + ((u >> 16) & 1u)) >> 16;   // RNE
  return (unsigned short)u;
}

// ---------------- A: fused convert + diagonal dots (reads v,t exactly once) ---------------
// A-side bf16 carries SCALE*LOG2E so GEMM scores come out in log2 domain.
__global__ void k_prep(const float* __restrict__ v, const float* __restrict__ t,
                       unsigned short* __restrict__ Abf, unsigned short* __restrict__ Bbf,
                       float* __restrict__ thr, float* __restrict__ nom,
                       float* __restrict__ out) {
  const int tid = threadIdx.x, l = tid & 63, w = tid >> 6;
  const int i = blockIdx.x * 4 + w;            // one wave per video
  if (blockIdx.x == 0 && tid < 5) out[tid] = 0.0f;
  const float AS = SCALE * LOG2E;

  float4 a = ((const float4*)(v + (size_t)i * D_K))[l];
  ushort4 oa;
  oa.x = f2bf(a.x * AS); oa.y = f2bf(a.y * AS);
  oa.z = f2bf(a.z * AS); oa.w = f2bf(a.w * AS);
  ((ushort4*)(Abf + (size_t)i * D_K))[l] = oa;

  float tv[T_PER];
#pragma unroll
  for (int tt = 0; tt < T_PER; ++tt) {
    float4 b = ((const float4*)(t + (size_t)(i * T_PER + tt) * D_K))[l];
    ushort4 ob;
    ob.x = f2bf(b.x); ob.y = f2bf(b.y); ob.z = f2bf(b.z); ob.w = f2bf(b.w);
    ((ushort4*)(Bbf + (size_t)(i * T_PER + tt) * D_K))[l] = ob;
    float d = a.x * b.x + a.y * b.y + a.z * b.z + a.w * b.w;
#pragma unroll
    for (int s = 1; s < 64; s <<= 1) d += __shfl_xor(d, s);
    tv[tt] = d * SCALE;                        // natural-domain score
  }
  if (l == 0) {
    ((float4*)thr)[i] = make_float4(tv[0] * LOG2E, tv[1] * LOG2E,
                                    tv[2] * LOG2E, tv[3] * LOG2E);
    float m = fmaxf(fmaxf(tv[0], tv[1]), fmaxf(tv[2], tv[3]));
    float e = __expf(tv[0] - m) + __expf(tv[1] - m) + __expf(tv[2] - m) + __expf(tv[3] - m);
    nom[i] = m + __logf(e);
  }
}

// ---------------- B: barrier-free K-loop GEMM --------------------------------------------
// Block = 64 rows x 256 cols. A (64x256, 32 KB, full K) staged to LDS ONCE (single
// __syncthreads). B fragments stream from global/L2, 2-deep cyclic prefetch so the
// compiler emits fine-grained vmcnt(N), never a collective vmcnt(0) barrier drain.
__device__ __forceinline__ void gld16(const void* g, void* l) {
  __builtin_amdgcn_global_load_lds((const __attribute__((address_space(1))) void*)g,
                                   (__attribute__((address_space(3))) void*)l,
                                   16, 0, 0);
}

__global__ __launch_bounds__(256, 4) void k_gemm(
    const unsigned short* __restrict__ Abf, const unsigned short* __restrict__ Bbf,
    const float* __restrict__ thr,
    float* __restrict__ pmax, float* __restrict__ psum, uint4* __restrict__ pcnt,
    float* __restrict__ cmax, float* __restrict__ csum) {
  __shared__ __align__(16) unsigned short As[64 * 256];   // 32 KB, swizzled full-K A tile
  __shared__ float4   thrS[64];
  __shared__ float    rowMw[4][64], rowEw[4][64];
  __shared__ uint32_t rowCw[4][64];

  const int ct = blockIdx.x, rt = blockIdx.y;
  const int row0 = rt * 64, col0 = ct * 256;
  const int tid = threadIdx.x;
  const int l = tid & 63, w = tid >> 6;
  const int quad = l >> 4, nl = l & 15;

  if (tid < 64) thrS[tid] = ((const float4*)thr)[row0 + tid];

  // ---- stage A once: 32 groups of 1024 B; group g = (rowset rs = g>>2, k-span ks = g&3).
  // Lane l = lr*8+lc writes 16B chunk (lc^lr) of row lr at slot l*16 (XOR swizzle keeps
  // both the wave-uniform gld16 placement AND conflict-free ds_read_b128 later).
  const int lr = l >> 3, lc7 = l & 7;
  const int sc = lc7 ^ lr;
#pragma unroll
  for (int it = 0; it < 8; ++it) {
    int g = w * 8 + it;
    int rs = g >> 2, ks = g & 3;
    const unsigned short* ga =
        Abf + (size_t)(row0 + rs * 8 + lr) * D_K + ks * 64 + sc * 8;
    gld16(ga, (char*)As + g * 1024);
  }

  f32x4 acc[4][4];
#pragma unroll
  for (int i = 0; i < 4; ++i)
#pragma unroll
    for (int j = 0; j < 4; ++j) acc[i][j] = {0.f, 0.f, 0.f, 0.f};

  // per-lane B pointers: col = col0 + w*64 + j*16 + nl, k = quad*8 (+ chunk offsets)
  const unsigned short* pB[4];
#pragma unroll
  for (int j = 0; j < 4; ++j)
    pB[j] = Bbf + (size_t)(col0 + w * 64 + j * 16 + nl) * D_K + quad * 8;

  __syncthreads();   // the ONLY barrier before the epilogue

  // 2-deep cyclic B prefetch (indices compile-time under full unroll)
  bf16x8 bv[3][4];
#pragma unroll
  for (int j = 0; j < 4; ++j) bv[0][j] = *(const bf16x8*)(pB[j]);
#pragma unroll
  for (int j = 0; j < 4; ++j) bv[1][j] = *(const bf16x8*)(pB[j] + 32);

#pragma unroll
  for (int c = 0; c < 8; ++c) {                 // 8 chunks of K=32
    if (c < 6) {
#pragma unroll
      for (int j = 0; j < 4; ++j)
        bv[(c + 2) % 3][j] = *(const bf16x8*)(pB[j] + (c + 2) * 32);
    }
    bf16x8 af[4];
#pragma unroll
    for (int i = 0; i < 4; ++i) {
      int r = i * 16 + nl;
      int rb = r & 7;
      int grp = (r >> 3) * 4 + (c >> 1);
      int cc = ((((c & 1) << 2) | quad) ^ rb);
      af[i] = *(const bf16x8*)((const char*)As + grp * 1024 + (rb * 8 + cc) * 16);
    }
#pragma unroll
    for (int i = 0; i < 4; ++i)
#pragma unroll
      for (int j = 0; j < 4; ++j)
        acc[i][j] = __builtin_amdgcn_mfma_f32_16x16x32_bf16(af[i], bv[c % 3][j],
                                                            acc[i][j], 0, 0, 0);
  }

  // ================= epilogue (scores in log2 domain) =================
  // C/D layout: col = nl, row = quad*4 + reg. Per-row/per-col maxes mandatory
  // (shared max underflows exp2 -> log(0) downstream).
  // Straight-line, branch-free; all 16-lane reduces are DPP rotation-reduces.

#pragma unroll
  for (int i = 0; i < 4; ++i) {
#pragma unroll
    for (int r = 0; r < 4; ++r) {
      const int row = i * 16 + quad * 4 + r;
      float4 th = thrS[row];                   // 16-lane broadcast read, conflict-free
      float s0 = acc[i][0][r], s1 = acc[i][1][r];
      float s2 = acc[i][2][r], s3 = acc[i][3][r];
      uint32_t c0 = (uint32_t)(s0 > th.x) + (uint32_t)(s1 > th.x)
                  + (uint32_t)(s2 > th.x) + (uint32_t)(s3 > th.x);
      uint32_t c1 = (uint32_t)(s0 > th.y) + (uint32_t)(s1 > th.y)
                  + (uint32_t)(s2 > th.y) + (uint32_t)(s3 > th.y);
      uint32_t c2 = (uint32_t)(s0 > th.z) + (uint32_t)(s1 > th.z)
                  + (uint32_t)(s2 > th.z) + (uint32_t)(s3 > th.z);
      uint32_t c3 = (uint32_t)(s0 > th.w) + (uint32_t)(s1 > th.w)
                  + (uint32_t)(s2 > th.w) + (uint32_t)(s3 > th.w);
      uint32_t c = c0 + (c1 << 8) + (c2 << 16) + (c3 << 24);
      c = sum16u(c);                           // fields <= 64, no overflow
      float m = fmaxf(fmaxf(s0, s1), fmaxf(s2, s3));
      m = max16(m);                            // all 16 lanes get the row max
      float e = (EXP2F(s0 - m) + EXP2F(s1 - m)) + (EXP2F(s2 - m) + EXP2F(s3 - m));
      e = sum16f(e);
      if (nl == 0) {
        rowMw[w][row] = m; rowEw[w][row] = e; rowCw[w][row] = c;
      }
    }
  }

  // col partials: whole 64-row column lives in this wave -> direct global write.
#pragma unroll
  for (int j = 0; j < 4; ++j) {
    float m = -3.0e38f;
#pragma unroll
    for (int i = 0; i < 4; ++i)
#pragma unroll
      for (int r = 0; r < 4; ++r) m = fmaxf(m, acc[i][j][r]);
    m = fmaxf(m, __shfl_xor(m, 16));
    m = fmaxf(m, __shfl_xor(m, 32));
    float e = 0.f;
#pragma unroll
    for (int i = 0; i < 4; ++i)
#pragma unroll
      for (int r = 0; r < 4; ++r) e += EXP2F(acc[i][j][r] - m);
    e += __shfl_xor(e, 16);
    e += __shfl_xor(e, 32);
    if (quad == 0) {
      int colg = col0 + w * 64 + j * 16 + nl;
      size_t gi = (size_t)rt * NT + colg;
      cmax[gi] = m; csum[gi] = e;
    }
  }
  __syncthreads();

  // combine the 4 col-strips per row; counts unpacked to 32-bit (4x64=256 would overflow 8b)
  if (tid < 64) {
    float M0 = rowMw[0][tid], M1 = rowMw[1][tid], M2 = rowMw[2][tid], M3 = rowMw[3][tid];
    float Mx = fmaxf(fmaxf(M0, M1), fmaxf(M2, M3));
    float Sx = rowEw[0][tid] * EXP2F(M0 - Mx) + rowEw[1][tid] * EXP2F(M1 - Mx)
             + rowEw[2][tid] * EXP2F(M2 - Mx) + rowEw[3][tid] * EXP2F(M3 - Mx);
    uint32_t c0 = 0, c1 = 0, c2 = 0, c3 = 0;
#pragma unroll
    for (int ww = 0; ww < 4; ++ww) {
      uint32_t cc = rowCw[ww][tid];
      c0 += cc & 0xffu; c1 += (cc >> 8) & 0xffu;
      c2 += (cc >> 16) & 0xffu; c3 += cc >> 24;
    }
    size_t gi = (size_t)ct * N_V + row0 + tid;
    pmax[gi] = Mx; psum[gi] = Sx; pcnt[gi] = make_uint4(c0, c1, c2, c3);
  }
}

// ---------------- C: fused row (64 partials) + col (64 partials) reductions ---------------
__global__ void k_red(const float* __restrict__ pmax, const float* __restrict__ psum,
                      const uint4* __restrict__ pcnt,
                      const float* __restrict__ cmax, const float* __restrict__ csum,
                      float* __restrict__ rowm, float* __restrict__ rows_,
                      uint4* __restrict__ rcnt,
                      float* __restrict__ colm, float* __restrict__ cols) {
  __shared__ float Lm[4][64], Ls[4][64];
  __shared__ uint4 Lc[4][64];
  __shared__ float Cm[2][128], Cs[2][128];
  const int bid = blockIdx.x, tid = threadIdx.x;
  if (bid < 64) {                      // rows: 64 blocks x 64 rows, 64 partials each
    int l = tid & 63, w = tid >> 6;
    int row = bid * 64 + l;
    float mv[16];
#pragma unroll
    for (int k = 0; k < 16; ++k)
      mv[k] = pmax[(size_t)(w * 16 + k) * N_V + row];
    float tm[8];
#pragma unroll
    for (int k = 0; k < 8; ++k) tm[k] = fmaxf(mv[k], mv[k + 8]);
#pragma unroll
    for (int k = 0; k < 4; ++k) tm[k] = fmaxf(tm[k], tm[k + 4]);
    float M = fmaxf(fmaxf(tm[0], tm[1]), fmaxf(tm[2], tm[3]));
    float S = 0.f;
    uint32_t c0 = 0, c1 = 0, c2 = 0, c3 = 0;
#pragma unroll
    for (int k = 0; k < 16; ++k) {
      size_t idx = (size_t)(w * 16 + k) * N_V + row;
      S += psum[idx] * EXP2F(mv[k] - M);
      uint4 cc = pcnt[idx];
      c0 += cc.x; c1 += cc.y; c2 += cc.z; c3 += cc.w;
    }
    Lm[w][l] = M; Ls[w][l] = S; Lc[w][l] = make_uint4(c0, c1, c2, c3);
    __syncthreads();
    if (tid < 64) {
      float M0 = Lm[0][tid], M1 = Lm[1][tid], M2 = Lm[2][tid], M3 = Lm[3][tid];
      float Mx = fmaxf(fmaxf(M0, M1), fmaxf(M2, M3));
      float Sx = Ls[0][tid] * EXP2F(M0 - Mx) + Ls[1][tid] * EXP2F(M1 - Mx)
               + Ls[2][tid] * EXP2F(M2 - Mx) + Ls[3][tid] * EXP2F(M3 - Mx);
      uint4 C = Lc[0][tid];
#pragma unroll
      for (int ww = 1; ww < 4; ++ww) {
        uint4 cc = Lc[ww][tid];
        C.x += cc.x; C.y += cc.y; C.z += cc.z; C.w += cc.w;
      }
      int r = bid * 64 + tid;
      rowm[r] = Mx; rows_[r] = Sx; rcnt[r] = C;
    }
  } else {                             // cols: 128 blocks x 128 cols, 64 partials each
    int cb = bid - 64;
    int c = tid & 127, h = tid >> 7;
    int col = cb * 128 + c;
    float mv[32];
#pragma unroll
    for (int k = 0; k < 32; ++k)
      mv[k] = cmax[(size_t)(h * 32 + k) * NT + col];
    float tm[16];
#pragma unroll
    for (int k = 0; k < 16; ++k) tm[k] = fmaxf(mv[k], mv[k + 16]);
#pragma unroll
    for (int k = 0; k < 8; ++k) tm[k] = fmaxf(tm[k], tm[k + 8]);
#pragma unroll
    for (int k = 0; k < 4; ++k) tm[k] = fmaxf(tm[k], tm[k + 4]);
    float M = fmaxf(fmaxf(tm[0], tm[1]), fmaxf(tm[2], tm[3]));
    float S = 0.f;
#pragma unroll
    for (int k = 0; k < 32; ++k)
      S += csum[(size_t)(h * 32 + k) * NT + col] * EXP2F(mv[k] - M);
    Cm[h][c] = M; Cs[h][c] = S;
    __syncthreads();
    if (tid < 128) {
      float M0 = Cm[0][tid], S0 = Cs[0][tid];
      float M1 = Cm[1][tid], S1 = Cs[1][tid];
      float Mx = fmaxf(M0, M1);
      float Sx = S0 * EXP2F(M0 - Mx) + S1 * EXP2F(M1 - Mx);
      int cg = cb * 128 + tid;
      colm[cg] = Mx; cols[cg] = Sx;
    }
  }
}

// ---------------- D: combine per row, loss + metrics, atomic means -------------------------
__global__ void k_final(const float* __restrict__ rowm, const float* __restrict__ rows_,
                        const uint4* __restrict__ rcnt, const float* __restrict__ nom,
                        const float* __restrict__ colm, const float* __restrict__ cols,
                        float* __restrict__ out) {
  int row = blockIdx.x * 256 + threadIdx.x;
  float M = rowm[row], S = rows_[row];
  float cm0 = colm[row * 4 + 0], cm1 = colm[row * 4 + 1];
  float cm2 = colm[row * 4 + 2], cm3 = colm[row * 4 + 3];
  float cs0 = cols[row * 4 + 0], cs1 = cols[row * 4 + 1];
  float cs2 = cols[row * 4 + 2], cs3 = cols[row * 4 + 3];
  float Mp = fmaxf(M, fmaxf(fmaxf(cm0, cm1), fmaxf(cm2, cm3)));
  float tot = S * EXP2F(M - Mp)
            + cs0 * EXP2F(cm0 - Mp) + cs1 * EXP2F(cm1 - Mp)
            + cs2 * EXP2F(cm2 - Mp) + cs3 * EXP2F(cm3 - Mp);
  // scores in log2 domain: natural-log LSE = LN2 * (Mp + log2(tot))
  float ll = LN2 * (Mp + __log2f(tot)) - nom[row];
  uint4 c = rcnt[row];
  float ar  = (float)(c.x + c.y + c.z + c.w) * 0.25f;
  float r1  = (float)((c.x < 1u) + (c.y < 1u) + (c.z < 1u) + (c.w < 1u)) * 0.25f;
  float r5  = (float)((c.x < 5u) + (c.y < 5u) + (c.z < 5u) + (c.w < 5u)) * 0.25f;
  float r10 = (float)((c.x < 10u) + (c.y < 10u) + (c.z < 10u) + (c.w < 10u)) * 0.25f;
  float vals[5] = {ll, r1, r5, r10, ar};
  int l = threadIdx.x & 63;
#pragma unroll
  for (int k = 0; k < 5; ++k) {
    float v = vals[k];
#pragma unroll
    for (int d = 1; d < 64; d <<= 1) v += __shfl_xor(v, d);
    if (l == 0) atomicAdd(&out[k], v * (1.0f / N_V));
  }
}

extern "C" void kernel_launch(void* const* d_in, const int* in_sizes, int n_in,
                              void* d_out, int out_size, void* d_ws, size_t ws_size,
                              hipStream_t stream) {
  const float* v = (const float*)d_in[0];
  const float* t = (const float*)d_in[1];
  char* p = (char*)d_ws;
  unsigned short* Abf = (unsigned short*)p; p += (size_t)N_V * D_K * 2;
  unsigned short* Bbf = (unsigned short*)p; p += (size_t)NT * D_K * 2;
  float* thr  = (float*)p;    p += (size_t)N_V * 4 * 4;
  float* nom  = (float*)p;    p += (size_t)N_V * 4;
  float* pmax = (float*)p;    p += (size_t)64 * N_V * 4;
  float* psum = (float*)p;    p += (size_t)64 * N_V * 4;
  uint4* pcnt = (uint4*)p;    p += (size_t)64 * N_V * 16;
  float* cmaxp = (float*)p;   p += (size_t)64 * NT * 4;
  float* csump = (float*)p;   p += (size_t)64 * NT * 4;
  float* rowm = (float*)p;    p += (size_t)N_V * 4;
  float* rows_ = (float*)p;   p += (size_t)N_V * 4;
  uint4* rcnt = (uint4*)p;    p += (size_t)N_V * 16;
  float* colm = (float*)p;    p += (size_t)NT * 4;
  float* cols = (float*)p;    p += (size_t)NT * 4;
  // total ws: ~26 MB

  k_prep<<<N_V / 4, 256, 0, stream>>>(v, t, Abf, Bbf, thr, nom, (float*)d_out);
  dim3 g(NT / 256, N_V / 64);                     // ct x rt = 64 x 64
  k_gemm<<<g, 256, 0, stream>>>(Abf, Bbf, thr, pmax, psum, pcnt, cmaxp, csump);
  k_red<<<64 + NT / 128, 256, 0, stream>>>(pmax, psum, pcnt, cmaxp, csump,
                                           rowm, rows_, rcnt, colm, cols);
  k_final<<<N_V / 256, 256, 0, stream>>>(rowm, rows_, rcnt, nom, colm, cols, (float*)d_out);
}